// Round 15
// baseline (268.588 us; speedup 1.0000x reference)
//
#include <hip/hip_runtime.h>
#include <math.h>

#define Mq 40000
#define Cc 128
#define Hh 16
#define Kk 15

typedef unsigned int uint32;
typedef unsigned short ushortT;
typedef short bf16x8 __attribute__((ext_vector_type(8)));
typedef float f32x4 __attribute__((ext_vector_type(4)));

static __device__ __forceinline__ uint32 f2bf_rne(float f) {
    union { float f; uint32 u; } v; v.f = f;
    return (v.u + 0x7FFFu + ((v.u >> 16) & 1u)) >> 16;
}
static __device__ __forceinline__ float bflo(uint32 u) { return __uint_as_float(u << 16); }
static __device__ __forceinline__ float bfhi(uint32 u) { return __uint_as_float(u & 0xFFFF0000u); }
static __device__ __forceinline__ uint32 cvtpk(float a, float b) {
    uint32 r; asm("v_cvt_pk_bf16_f32 %0, %1, %2" : "=v"(r) : "v"(a), "v"(b)); return r;
}
// wave-local LDS fence: all this wave's prior ds ops complete & visible to all
// its lanes; sched_barrier stops the compiler hoisting dependent ops above it.
// NOTE: waits lgkmcnt ONLY — global loads (vmcnt) stay in flight across it,
// which is what lets the cross-query gather pipeline work.
#define WAVE_FENCE() do { \
    asm volatile("s_waitcnt lgkmcnt(0)" ::: "memory"); \
    __builtin_amdgcn_sched_barrier(0); } while (0)

// ---------------------------------------------------------------------------
// prepW: wT[n][k] = bf16(concat(Wq,Wk)[k][n])   (16 blocks, trivial)
// ---------------------------------------------------------------------------
__global__ __launch_bounds__(256) void prepW(
    const float* __restrict__ Wq, const float* __restrict__ Wk,
    ushortT* __restrict__ wT)
{
    const int j = blockIdx.x * 256 + threadIdx.x;   // 0..4095
    const int k = j >> 5;                           // 0..127
    const int n0 = (j & 31) * 8;                    // 0..248, no q/k crossing
    const float* __restrict__ src = (n0 < 128) ? (Wq + k * 128 + n0)
                                               : (Wk + k * 128 + n0 - 128);
    #pragma unroll
    for (int e = 0; e < 8; ++e)
        wT[(n0 + e) * 128 + k] = (ushortT)f2bf_rne(src[e]);
}

// ---------------------------------------------------------------------------
// qk_gemm (MFMA, LDS-free, fused s_bf16 production) — unchanged from r6.
// ---------------------------------------------------------------------------
__global__ __launch_bounds__(256, 4) void qk_gemm(
    const float* __restrict__ s_feats, const ushortT* __restrict__ wT,
    const float* __restrict__ bq, const float* __restrict__ bk,
    ushortT* __restrict__ s_bf16, ushortT* __restrict__ q_bf16,
    ushortT* __restrict__ k_bf16)
{
    const int tid = threadIdx.x;
    const int w = tid >> 6, l = tid & 63;
    const int lo = l & 15, hi = l >> 4;
    const int r0 = blockIdx.x * 64 + w * 16;

    bf16x8 af[4];
    #pragma unroll
    for (int kt = 0; kt < 4; ++kt) {
        const float* __restrict__ p = s_feats + (size_t)(r0 + lo) * Cc + kt * 32 + hi * 8;
        const float4 x = *(const float4*)p;
        const float4 y = *(const float4*)(p + 4);
        uint32 u[4] = {cvtpk(x.x, x.y), cvtpk(x.z, x.w),
                       cvtpk(y.x, y.y), cvtpk(y.z, y.w)};
        af[kt] = *(bf16x8*)u;
        *(uint4*)(s_bf16 + (size_t)(r0 + lo) * Cc + kt * 32 + hi * 8) = *(uint4*)u;
    }

    #pragma unroll
    for (int ns = 0; ns < 16; ++ns) {
        const int n = ns * 16 + lo;                   // output col over [q|k]
        const float bv = (n < 128) ? bq[n] : bk[n - 128];
        f32x4 acc = (f32x4){bv, bv, bv, bv};
        #pragma unroll
        for (int kt = 0; kt < 4; ++kt) {
            const bf16x8 bf = *(const bf16x8*)(wT + n * Cc + kt * 32 + hi * 8);
            acc = __builtin_amdgcn_mfma_f32_16x16x32_bf16(af[kt], bf, acc, 0, 0, 0);
        }
        ushortT* __restrict__ tbl = (ns < 8) ? q_bf16 : k_bf16;  // uniform (lo<16)
        const int col = n & 127;
        #pragma unroll
        for (int r = 0; r < 4; ++r)                   // D: row=(l>>4)*4+r, col=l&15
            tbl[(size_t)(r0 + hi * 4 + r) * Cc + col] = (ushortT)f2bf_rne(acc[r]);
    }
}

// ---------------------------------------------------------------------------
// kpt_main: 2500 blocks x 4 waves; wave = 4 queries, SOFTWARE-PIPELINED:
// gathers for query qq+1 are issued before computing query qq (T14 split),
// so HBM latency hides under the previous query's MLP+aggregate.
// All query-loop LDS is wave-private -> WAVE_FENCE only, no __syncthreads.
// ---------------------------------------------------------------------------
__global__ __launch_bounds__(256, 4) void kpt_main(
    const float* __restrict__ q_pts, const float* __restrict__ s_pts,
    const ushortT* __restrict__ s_bf16, const int* __restrict__ nb,
    const float* __restrict__ kpts, const float* __restrict__ wkp,
    const float* __restrict__ w1, const float* __restrict__ w2,
    const float* __restrict__ b2,
    const ushortT* __restrict__ q_bf16, const ushortT* __restrict__ k_bf16,
    float* __restrict__ out)
{
    __shared__ __align__(16) uint32 wt_lds[Kk][64];   // kp weights, bf16 pairs (cross-wave)
    __shared__ __align__(16) float  kpl[45];
    __shared__ __align__(16) uint32 a_u[4][1024];     // per-wave 16x128 bf16, swizzled
    __shared__ __align__(16) float  t_scr[4][16][20]; // 16 cols + pad (K-pad in regs)
    __shared__ __align__(16) float  sg_scr[4][16][18];// sigmoid*infl
    __shared__ __align__(16) int    id_l[4][4][16];   // id | (nn<<20)
    __shared__ __align__(16) float  in_l[4][4][16];   // influence

    const int tid = threadIdx.x;
    const int w = tid >> 6, l = tid & 63;
    const int lo = l & 15, hi = l >> 4;

    // ---- cross-wave staging (the ONLY __syncthreads) ----
    for (int i = tid; i < Kk * 64; i += 256) {
        const int k = i >> 6, c2 = i & 63;
        const float2 v = *(const float2*)(wkp + k * Cc + c2 * 2);
        wt_lds[k][c2] = cvtpk(v.x, v.y);
    }
    if (tid < 45) kpl[tid] = kpts[tid];
    __syncthreads();

    const int mq0 = blockIdx.x * 16 + w * 4;

    // ---- geometry: lane covers (qq=hi, h=lo) -> 4 queries in one pass ----
    {
        const int m = mq0 + hi, h = lo;
        const int id = nb[m * Hh + h];
        const float px = s_pts[id * 3 + 0] - q_pts[m * 3 + 0];
        const float py = s_pts[id * 3 + 1] - q_pts[m * 3 + 1];
        const float pz = s_pts[id * 3 + 2] - q_pts[m * 3 + 2];
        float best = 1e30f; int bi = 0;
        #pragma unroll
        for (int k = 0; k < Kk; ++k) {
            const float dx = px - kpl[k * 3 + 0];
            const float dy = py - kpl[k * 3 + 1];
            const float dz = pz - kpl[k * 3 + 2];
            const float d = dx * dx + dy * dy + dz * dz;
            if (d < best) { best = d; bi = k; }
        }
        id_l[w][hi][h] = id | (bi << 20);
        in_l[w][hi][h] = fmaxf(0.f, 1.f - sqrtf(best) * 0.5f);  // SIGMA=2
    }

    // ---- loop-invariant fragments ----
    bf16x8 w1f[4];                           // B-frag: w1[k][j], j=lane&15
    #pragma unroll
    for (int kt = 0; kt < 4; ++kt) {
        float tmp[8];
        #pragma unroll
        for (int e = 0; e < 8; ++e)
            tmp[e] = w1[(kt * 32 + hi * 8 + e) * 16 + lo];
        uint32 u[4] = {cvtpk(tmp[0], tmp[1]), cvtpk(tmp[2], tmp[3]),
                       cvtpk(tmp[4], tmp[5]), cvtpk(tmp[6], tmp[7])};
        w1f[kt] = *(bf16x8*)u;
    }
    bf16x8 w2f;                              // B-frag: w2[jp][j], jp>=16 -> 0
    {
        float tmp[8];
        #pragma unroll
        for (int e = 0; e < 8; ++e) {
            const int k = hi * 8 + e;
            tmp[e] = (k < 16) ? w2[k * 16 + lo] : 0.f;
        }
        uint32 u[4] = {cvtpk(tmp[0], tmp[1]), cvtpk(tmp[2], tmp[3]),
                       cvtpk(tmp[4], tmp[5]), cvtpk(tmp[6], tmp[7])};
        w2f = *(bf16x8*)u;
    }
    const float bias2 = b2[lo];
    WAVE_FENCE();                            // geometry id_l/in_l visible wave-wide

    // ---- cross-query register pipeline: sets indexed by qq&1 (static after
    // full unroll -> registers, rule #20). Prologue issues set 0. ----
    int    ids[2][16];
    uint32 kv[2][16], vv[2][16], qvv[2];

    #pragma unroll
    for (int h = 0; h < Hh; ++h) ids[0][h] = id_l[w][0][h];
    qvv[0] = *(const uint32*)(q_bf16 + (size_t)mq0 * Cc + 2 * l);
    #pragma unroll
    for (int h = 0; h < Hh; ++h) {
        const int id = ids[0][h] & 0xFFFFF;
        kv[0][h] = *(const uint32*)(k_bf16 + (size_t)id * Cc + 2 * l);
        vv[0][h] = *(const uint32*)(s_bf16 + (size_t)id * Cc + 2 * l);
    }

    #pragma unroll
    for (int qq = 0; qq < 4; ++qq) {
        const int cur = qq & 1, nxt = cur ^ 1;
        const int m = mq0 + qq;

        // issue-early: next query's 33 loads go out BEFORE this query's MLP
        if (qq < 3) {
            #pragma unroll
            for (int h = 0; h < Hh; ++h) ids[nxt][h] = id_l[w][qq + 1][h];
            qvv[nxt] = *(const uint32*)(q_bf16 + (size_t)(m + 1) * Cc + 2 * l);
            #pragma unroll
            for (int h = 0; h < Hh; ++h) {
                const int id = ids[nxt][h] & 0xFFFFF;
                kv[nxt][h] = *(const uint32*)(k_bf16 + (size_t)id * Cc + 2 * l);
                vv[nxt][h] = *(const uint32*)(s_bf16 + (size_t)id * Cc + 2 * l);
            }
        }

        const float q0 = bflo(qvv[cur]), q1 = bfhi(qvv[cur]);

        // a = leaky(q - k) -> swizzled LDS (word (h*64+l)^((h&7)<<2))
        #pragma unroll
        for (int h = 0; h < Hh; ++h) {
            float a0 = q0 - bflo(kv[cur][h]); a0 = fmaxf(a0, 0.1f * a0);
            float a1 = q1 - bfhi(kv[cur][h]); a1 = fmaxf(a1, 0.1f * a1);
            a_u[w][(h * 64 + l) ^ ((h & 7) << 2)] = cvtpk(a0, a1);
        }
        WAVE_FENCE();

        // linear1: A-frag row=l&15(h), k=(l>>4)*8+e
        f32x4 acc1 = {0.f, 0.f, 0.f, 0.f};
        #pragma unroll
        for (int kt = 0; kt < 4; ++kt) {
            const int boff = (lo * 256 + kt * 64 + hi * 16) ^ ((l & 7) << 4);
            const bf16x8 af = *(const bf16x8*)((const char*)&a_u[w][0] + boff);
            acc1 = __builtin_amdgcn_mfma_f32_16x16x32_bf16(af, w1f[kt], acc1, 0, 0, 0);
        }
        #pragma unroll
        for (int r = 0; r < 4; ++r) {        // D: row=h=(l>>4)*4+r, col=j=l&15
            const float v = acc1[r];
            t_scr[w][hi * 4 + r][lo] = fmaxf(v, 0.1f * v);
        }
        WAVE_FENCE();

        // linear2: A-frag = t rows; k>=16 half is register zeros
        f32x4 acc2 = {bias2, bias2, bias2, bias2};
        {
            uint32 u0 = 0, u1 = 0, u2 = 0, u3 = 0;
            if (hi < 2) {
                const float4 ta = *(const float4*)&t_scr[w][lo][hi * 8];
                const float4 tb = *(const float4*)&t_scr[w][lo][hi * 8 + 4];
                u0 = cvtpk(ta.x, ta.y); u1 = cvtpk(ta.z, ta.w);
                u2 = cvtpk(tb.x, tb.y); u3 = cvtpk(tb.z, tb.w);
            }
            uint32 uu[4] = {u0, u1, u2, u3};
            const bf16x8 tf = *(const bf16x8*)uu;
            acc2 = __builtin_amdgcn_mfma_f32_16x16x32_bf16(tf, w2f, acc2, 0, 0, 0);
        }
        #pragma unroll
        for (int r = 0; r < 4; ++r) {        // fold influence into stored gate
            const float s = 1.f / (1.f + __expf(-acc2[r]));
            sg_scr[w][hi * 4 + r][lo] = s * in_l[w][qq][hi * 4 + r];
        }
        WAVE_FENCE();

        // aggregate: out[c] = sum_h v*wkp[nn]*infl*sig, lane owns c=2l,2l+1
        float o0 = 0.f, o1 = 0.f;
        #pragma unroll
        for (int h = 0; h < Hh; ++h) {
            const uint32 wp = wt_lds[ids[cur][h] >> 20][l];
            const float2 sp = *(const float2*)&sg_scr[w][h][2 * (l & 7)];
            o0 = fmaf(bflo(vv[cur][h]) * bflo(wp), sp.x, o0);
            o1 = fmaf(bfhi(vv[cur][h]) * bfhi(wp), sp.y, o1);
        }
        *(float2*)(out + (size_t)m * Cc + 2 * l) = make_float2(o0, o1);
        // WAR on a_u next iter: same-wave program order + fences
    }
}

extern "C" void kernel_launch(void* const* d_in, const int* in_sizes, int n_in,
                              void* d_out, int out_size, void* d_ws, size_t ws_size,
                              hipStream_t stream) {
    const float* q_pts   = (const float*)d_in[0];
    const float* s_pts   = (const float*)d_in[1];
    const float* s_feats = (const float*)d_in[2];
    const int*   nb      = (const int*)d_in[3];
    const float* kpts    = (const float*)d_in[4];
    const float* wkp     = (const float*)d_in[5];
    const float* Wq      = (const float*)d_in[6];
    const float* bq      = (const float*)d_in[7];
    const float* Wk      = (const float*)d_in[8];
    const float* bk      = (const float*)d_in[9];
    const float* w1      = (const float*)d_in[10];
    const float* w2      = (const float*)d_in[11];
    const float* b2      = (const float*)d_in[12];
    float* outp = (float*)d_out;

    ushortT* s_bf16 = (ushortT*)d_ws;                         // 10.24 MB
    ushortT* q_bf16 = s_bf16 + (size_t)Mq * Cc;               // 10.24 MB
    ushortT* k_bf16 = q_bf16 + (size_t)Mq * Cc;               // 10.24 MB
    ushortT* wT     = k_bf16 + (size_t)Mq * Cc;               // 64 KB

    prepW   <<<16,   256, 0, stream>>>(Wq, Wk, wT);
    qk_gemm <<<625,  256, 0, stream>>>(s_feats, wT, bq, bk, s_bf16, q_bf16, k_bf16);
    kpt_main<<<2500, 256, 0, stream>>>(q_pts, s_pts, s_bf16, nb, kpts, wkp,
                                       w1, w2, b2, q_bf16, k_bf16, outp);
}